// Round 4
// baseline (1217.899 us; speedup 1.0000x reference)
//
#include <hip/hip_runtime.h>

typedef __bf16 bf16x8 __attribute__((ext_vector_type(8)));
typedef float f32x4 __attribute__((ext_vector_type(4)));

__device__ __forceinline__ float b2f(unsigned short u) {
    union { unsigned int i; float f; } v; v.i = ((unsigned int)u) << 16; return v.f;
}
__device__ __forceinline__ unsigned short f2b(float f) {
    union { float f; unsigned int i; } v; v.f = f;
    unsigned int r = (v.i + 0x7fffu + ((v.i >> 16) & 1u)) >> 16;
    return (unsigned short)r;
}

// async global -> LDS, 16B per lane. LDS dest is wave-uniform base + lane*16.
__device__ __forceinline__ void gload16(const void* g, void* l) {
    __builtin_amdgcn_global_load_lds(
        (const __attribute__((address_space(1))) unsigned int*)g,
        (__attribute__((address_space(3))) unsigned int*)l,
        16, 0, 0);
}

// XCD-chunked block mapping (T1): blocks sharing an A row-panel (same bx, all
// by) run back-to-back on the SAME XCD -> panel fetched into that XCD's L2
// once. Bijective when nx%8==0: bid=(xcd, s), s=(xl, by); bx=xcd*(nx/8)+xl.
__device__ __forceinline__ void xcd_map(int bid, int nx, int ny, int& bx, int& by) {
    if ((nx & 7) == 0) {
        int xcd = bid & 7;
        int s   = bid >> 3;
        int xl  = s / ny;
        by = s - xl * ny;
        bx = xcd * (nx >> 3) + xl;
    } else {
        bx = bid / ny;
        by = bid - bx * ny;
    }
}

// ---------------------------------------------------------------------------
// Convert the 5 weight matrices f32 -> bf16 into workspace (once per launch).
// ---------------------------------------------------------------------------
__global__ __launch_bounds__(256)
void k_cvt5(const float* __restrict__ s0, const float* __restrict__ s1,
            const float* __restrict__ s2, const float* __restrict__ s3,
            const float* __restrict__ s4, unsigned short* __restrict__ dst)
{
    size_t gid = ((size_t)blockIdx.x * 256 + threadIdx.x) * 4;
    const float* src; size_t off;
    if      (gid < 196608) { src = s0; off = 0; }
    else if (gid < 262144) { src = s1; off = 196608; }
    else if (gid < 524288) { src = s2; off = 262144; }
    else if (gid < 786432) { src = s3; off = 524288; }
    else                   { src = s4; off = 786432; }
    float4 v = *(const float4*)(src + (gid - off));
    uint2 pk;
    pk.x = (unsigned int)f2b(v.x) | ((unsigned int)f2b(v.y) << 16);
    pk.y = (unsigned int)f2b(v.z) | ((unsigned int)f2b(v.w) << 16);
    *(uint2*)(dst + gid) = pk;
}

// ---------------------------------------------------------------------------
// Kernel 1: h = rmsnorm(x, norm1_w); xpe = h + rel @ pe_w^T + pe_b  (bf16 out)
// ---------------------------------------------------------------------------
__global__ __launch_bounds__(256)
void k_norm1_pe(const float* __restrict__ x,
                const float* __restrict__ pos,
                const float* __restrict__ n1w,
                const float* __restrict__ pew,
                const float* __restrict__ peb,
                unsigned short* __restrict__ out)
{
    __shared__ float spw0[256], spw1[256], spw2[256], speb[256], snw[256];
    __shared__ float px[128], py[128], pz[128];
    __shared__ float mean[3];
    const int tid = threadIdx.x;
    const int ball = blockIdx.x;

    spw0[tid] = pew[tid*3+0]; spw1[tid] = pew[tid*3+1]; spw2[tid] = pew[tid*3+2];
    speb[tid] = peb[tid];     snw[tid]  = n1w[tid];
    if (tid < 128) {
        const float* pp = pos + (size_t)(ball*128 + tid)*3;
        px[tid] = pp[0]; py[tid] = pp[1]; pz[tid] = pp[2];
    }
    __syncthreads();
    if (tid < 3) {
        const float* arr = (tid==0) ? px : (tid==1) ? py : pz;
        float s = 0.f;
        for (int i = 0; i < 128; ++i) s += arr[i];
        mean[tid] = s * (1.0f/128.0f);
    }
    __syncthreads();

    const int wave = tid >> 6, lane = tid & 63;
    const float m0 = mean[0], m1 = mean[1], m2 = mean[2];
    for (int tok = wave; tok < 128; tok += 4) {
        size_t row = (size_t)(ball*128 + tok);
        float4 xv = *(const float4*)(x + row*256 + lane*4);
        float xf[4] = { xv.x, xv.y, xv.z, xv.w };
        float ss = xf[0]*xf[0] + xf[1]*xf[1] + xf[2]*xf[2] + xf[3]*xf[3];
        #pragma unroll
        for (int off = 1; off < 64; off <<= 1) ss += __shfl_xor(ss, off);
        float rstd = rsqrtf(ss * (1.0f/256.0f) + 1e-6f);
        float r0 = px[tok] - m0, r1 = py[tok] - m1, r2 = pz[tok] - m2;
        unsigned short o[4];
        #pragma unroll
        for (int k = 0; k < 4; ++k) {
            int j = lane*4 + k;
            float hv = xf[k] * rstd * snw[j];
            o[k] = f2b(hv + r0*spw0[j] + r1*spw1[j] + r2*spw2[j] + speb[j]);
        }
        uint2 pk;
        pk.x = (unsigned int)o[0] | ((unsigned int)o[1] << 16);
        pk.y = (unsigned int)o[2] | ((unsigned int)o[3] << 16);
        *(uint2*)(out + row*256 + lane*4) = pk;
    }
}

// ---------------------------------------------------------------------------
// rmsnorm only (norm2): f32 in, bf16 out, wave-per-token
// ---------------------------------------------------------------------------
__global__ __launch_bounds__(256)
void k_rmsnorm(const float* __restrict__ x,
               const float* __restrict__ w,
               unsigned short* __restrict__ out)
{
    const int lane = threadIdx.x & 63;
    const size_t token = (size_t)blockIdx.x*4 + (threadIdx.x >> 6);
    float4 xv = *(const float4*)(x + token*256 + lane*4);
    float xf[4] = { xv.x, xv.y, xv.z, xv.w };
    float ss = xf[0]*xf[0] + xf[1]*xf[1] + xf[2]*xf[2] + xf[3]*xf[3];
    #pragma unroll
    for (int off = 1; off < 64; off <<= 1) ss += __shfl_xor(ss, off);
    float rstd = rsqrtf(ss * (1.0f/256.0f) + 1e-6f);
    float4 wv = *(const float4*)(w + lane*4);
    unsigned short o[4] = { f2b(xf[0]*rstd*wv.x), f2b(xf[1]*rstd*wv.y),
                            f2b(xf[2]*rstd*wv.z), f2b(xf[3]*rstd*wv.w) };
    uint2 pk;
    pk.x = (unsigned int)o[0] | ((unsigned int)o[1] << 16);
    pk.y = (unsigned int)o[2] | ((unsigned int)o[3] << 16);
    *(uint2*)(out + token*256 + lane*4) = pk;
}

// ---------------------------------------------------------------------------
// GEMM mainloop: C(128x128) = A(M,K) @ B(N,K)^T, bf16, fp32 acc.
// Round-2 proven 2-barrier single-buffer schedule + round-3 verified
// fragment-ordered LDS (conflict-free):
//  - each 16x32 subtile stored so LDS slot lane*16B holds exactly lane's
//    MFMA fragment (row=lane&15, kchunk=lane>>4); gload_lds writes linear,
//    the PERMUTATION lives in the per-lane GLOBAL source address.
//  - fragment ds_read_b128 = subtile*1024B + lane*16B: dense, 0 conflicts
//    (verified round 3: SQ_LDS_BANK_CONFLICT == 0).
// ---------------------------------------------------------------------------
__device__ __forceinline__ void gemm_mainloop_bt(
    const unsigned short* __restrict__ A, const unsigned short* __restrict__ B,
    int K, int m0, int n0, int tid,
    unsigned short* sA, unsigned short* sB, f32x4 (&acc)[4][4])
{
    const int lane = tid & 63;
    const int wave = tid >> 6;
    // wave stages subtiles {2w, 2w+1}; lane -> (row = lane&15, col = (lane>>4)*8)
    const int srow = wave * 32 + (lane & 15);
    const int scol = (lane >> 4) * 8;
    const unsigned short* pA = A + (size_t)(m0 + srow) * K + scol;
    const unsigned short* pB = B + (size_t)(n0 + srow) * K + scol;
    const size_t row16 = (size_t)16 * K;
    unsigned short* lA = sA + wave * 1024;
    unsigned short* lB = sB + wave * 1024;
    const int aBase = (wave >> 1) * 2048 + lane * 8;   // + i*512
    const int bBase = (wave & 1) * 2048 + lane * 8;    // + j*512

    for (int k0 = 0; k0 < K; k0 += 32) {
        __syncthreads();
        gload16(pA + k0,         lA);
        gload16(pA + row16 + k0, lA + 512);
        gload16(pB + k0,         lB);
        gload16(pB + row16 + k0, lB + 512);
        __syncthreads();   // vmcnt(0) drain = tile handoff
        bf16x8 af[4], bfr[4];
        #pragma unroll
        for (int i = 0; i < 4; ++i) af[i]  = *(const bf16x8*)&sA[aBase + i*512];
        #pragma unroll
        for (int j = 0; j < 4; ++j) bfr[j] = *(const bf16x8*)&sB[bBase + j*512];
        #pragma unroll
        for (int i = 0; i < 4; ++i)
            #pragma unroll
            for (int j = 0; j < 4; ++j)
                acc[i][j] = __builtin_amdgcn_mfma_f32_16x16x32_bf16(af[i], bfr[j], acc[i][j], 0, 0, 0);
    }
}

// Generic GEMM + f32 bias (+ optional f32 residual); output bf16 or f32.
__global__ __launch_bounds__(256, 2)
void k_gemm_bias(const unsigned short* __restrict__ A,
                 const unsigned short* __restrict__ B,
                 const float* __restrict__ bias,
                 const float* residual,
                 void* C, int K, int Ncols, int outBf16, int ny)
{
    __shared__ __align__(16) unsigned short sA[128*32];
    __shared__ __align__(16) unsigned short sB[128*32];
    const int tid = threadIdx.x;
    int bx, by;
    xcd_map(blockIdx.x, gridDim.x / ny, ny, bx, by);
    const int m0 = bx * 128, n0 = by * 128;
    f32x4 zero = {0.f, 0.f, 0.f, 0.f};
    f32x4 acc[4][4];
    #pragma unroll
    for (int i = 0; i < 4; ++i)
        #pragma unroll
        for (int j = 0; j < 4; ++j) acc[i][j] = zero;

    gemm_mainloop_bt(A, B, K, m0, n0, tid, sA, sB, acc);

    const int lane = tid & 63, lane16 = lane & 15, quad = lane >> 4;
    const int wave = tid >> 6, wm = (wave >> 1) * 64, wn = (wave & 1) * 64;
    #pragma unroll
    for (int i = 0; i < 4; ++i)
        #pragma unroll
        for (int j = 0; j < 4; ++j) {
            int n = n0 + wn + j*16 + lane16;
            float bj = bias[n];
            #pragma unroll
            for (int r = 0; r < 4; ++r) {
                int m = m0 + wm + i*16 + quad*4 + r;
                size_t idx = (size_t)m * Ncols + n;
                float v = acc[i][j][r] + bj;
                if (residual) v += residual[idx];
                if (outBf16) ((unsigned short*)C)[idx] = f2b(v);
                else         ((float*)C)[idx] = v;
            }
        }
}

// ---------------------------------------------------------------------------
// SwiGLU dual GEMM: gv = silu(A@B1^T + b1) * (A@B2^T + b2) -> bf16, Ncols=1024
// Block tile 128x64, wave tile 64x32; fragment-ordered LDS, 2-barrier loop.
// Wave stages A subtiles {2w,2w+1}, B1 subtile {w}, B2 subtile {w}.
// ---------------------------------------------------------------------------
__global__ __launch_bounds__(256, 3)
void k_gemm_swiglu(const unsigned short* __restrict__ A,
                   const unsigned short* __restrict__ B1,
                   const unsigned short* __restrict__ B2,
                   const float* __restrict__ b1,
                   const float* __restrict__ b2,
                   unsigned short* __restrict__ C, int K, int ny)
{
    __shared__ __align__(16) unsigned short sA[128*32];
    __shared__ __align__(16) unsigned short sB1[64*32];
    __shared__ __align__(16) unsigned short sB2[64*32];
    const int tid = threadIdx.x;
    int bx, by;
    xcd_map(blockIdx.x, gridDim.x / ny, ny, bx, by);
    const int m0 = bx * 128, n0 = by * 64;
    const int lane = tid & 63, lane16 = lane & 15, quad = lane >> 4;
    const int wave = tid >> 6;
    const int wm = (wave >> 1) * 64, wn = (wave & 1) * 32;
    const int srowA = wave * 32 + (lane & 15);
    const int srowB = wave * 16 + (lane & 15);
    const int scol  = (lane >> 4) * 8;
    const unsigned short* pA  = A  + (size_t)(m0 + srowA) * K + scol;
    const unsigned short* pB1 = B1 + (size_t)(n0 + srowB) * K + scol;
    const unsigned short* pB2 = B2 + (size_t)(n0 + srowB) * K + scol;
    const size_t row16 = (size_t)16 * K;
    unsigned short* lA  = sA  + wave * 1024;
    unsigned short* lB1 = sB1 + wave * 512;
    unsigned short* lB2 = sB2 + wave * 512;
    const int aBase = (wave >> 1) * 2048 + lane * 8;   // + i*512, i<4
    const int bBase = (wave & 1) * 1024 + lane * 8;    // + j*512, j<2

    f32x4 zero = {0.f, 0.f, 0.f, 0.f};
    f32x4 accg[4][2], accv[4][2];
    #pragma unroll
    for (int i = 0; i < 4; ++i)
        #pragma unroll
        for (int j = 0; j < 2; ++j) { accg[i][j] = zero; accv[i][j] = zero; }

    for (int k0 = 0; k0 < K; k0 += 32) {
        __syncthreads();
        gload16(pA + k0,         lA);
        gload16(pA + row16 + k0, lA + 512);
        gload16(pB1 + k0,        lB1);
        gload16(pB2 + k0,        lB2);
        __syncthreads();
        bf16x8 af[4], bg[2], bv[2];
        #pragma unroll
        for (int i = 0; i < 4; ++i) af[i] = *(const bf16x8*)&sA[aBase + i*512];
        #pragma unroll
        for (int j = 0; j < 2; ++j) {
            bg[j] = *(const bf16x8*)&sB1[bBase + j*512];
            bv[j] = *(const bf16x8*)&sB2[bBase + j*512];
        }
        #pragma unroll
        for (int i = 0; i < 4; ++i)
            #pragma unroll
            for (int j = 0; j < 2; ++j) {
                accg[i][j] = __builtin_amdgcn_mfma_f32_16x16x32_bf16(af[i], bg[j], accg[i][j], 0, 0, 0);
                accv[i][j] = __builtin_amdgcn_mfma_f32_16x16x32_bf16(af[i], bv[j], accv[i][j], 0, 0, 0);
            }
    }

    #pragma unroll
    for (int i = 0; i < 4; ++i)
        #pragma unroll
        for (int j = 0; j < 2; ++j) {
            int n = n0 + wn + j*16 + lane16;
            float bjg = b1[n], bjv = b2[n];
            #pragma unroll
            for (int r = 0; r < 4; ++r) {
                int m = m0 + wm + i*16 + quad*4 + r;
                float g  = accg[i][j][r] + bjg;
                float vv = accv[i][j][r] + bjv;
                float sg = 1.0f / (1.0f + __expf(-g));
                C[(size_t)m * 1024 + n] = f2b(g * sg * vv);
            }
        }
}

// ---------------------------------------------------------------------------
// Attention: one block per (ball, head). 256 threads = 4 waves.
// ---------------------------------------------------------------------------
__global__ __launch_bounds__(256, 2)
void k_attn(const unsigned short* __restrict__ qkv,
            const float* __restrict__ pos,
            const float* __restrict__ sigma,
            unsigned short* __restrict__ out)
{
    __shared__ __align__(16) unsigned short Qs[128*40];
    __shared__ __align__(16) unsigned short Ks[128*40];
    __shared__ __align__(16) unsigned short Vt[32*136];
    __shared__ __align__(16) unsigned short Ps[128*136];
    __shared__ float px[128], py[128], pz[128];

    int ball, h;
    xcd_map(blockIdx.x, gridDim.x >> 3, 8, ball, h);
    const int tid  = threadIdx.x;

    {
        int tok = tid >> 1;
        int e0  = (tid & 1) * 16;
        const unsigned short* rowp = qkv + (size_t)(ball*128 + tok)*768 + h*96 + e0*3;
        unsigned short u[48];
        #pragma unroll
        for (int c = 0; c < 6; ++c) *(uint4*)&u[c*8] = *(const uint4*)(rowp + c*8);
        #pragma unroll
        for (int e = 0; e < 16; ++e) {
            Qs[tok*40 + e0 + e]    = u[e*3 + 0];
            Ks[tok*40 + e0 + e]    = u[e*3 + 1];
            Vt[(e0 + e)*136 + tok] = u[e*3 + 2];
        }
    }
    if (tid < 128) {
        const float* pp = pos + (size_t)(ball*128 + tid)*3;
        px[tid] = pp[0]; py[tid] = pp[1]; pz[tid] = pp[2];
    }
    __syncthreads();

    const int wave = tid >> 6, lane = tid & 63, lane16 = lane & 15, quad = lane >> 4;
    const float sig = sigma[h];
    const float scale = 0.17677669529663687f;  // 1/sqrt(32)
    f32x4 zero = {0.f, 0.f, 0.f, 0.f};

    f32x4 s[2][8];
    {
        bf16x8 a[2];
        #pragma unroll
        for (int i = 0; i < 2; ++i)
            a[i] = *(const bf16x8*)&Qs[(wave*32 + i*16 + lane16)*40 + quad*8];
        #pragma unroll
        for (int j = 0; j < 8; ++j) {
            bf16x8 b = *(const bf16x8*)&Ks[(j*16 + lane16)*40 + quad*8];
            #pragma unroll
            for (int i = 0; i < 2; ++i)
                s[i][j] = __builtin_amdgcn_mfma_f32_16x16x32_bf16(a[i], b, zero, 0, 0, 0);
        }
    }

    float pnx[8], pny[8], pnz[8];
    #pragma unroll
    for (int j = 0; j < 8; ++j) {
        int n = j*16 + lane16;
        pnx[j] = px[n]; pny[j] = py[n]; pnz[j] = pz[n];
    }
    float l[2][4];
    #pragma unroll
    for (int i = 0; i < 2; ++i)
        #pragma unroll
        for (int r = 0; r < 4; ++r) {
            int m = wave*32 + i*16 + quad*4 + r;
            float pmx = px[m], pmy = py[m], pmz = pz[m];
            float sv[8];
            float mx = -1e30f;
            #pragma unroll
            for (int j = 0; j < 8; ++j) {
                float dx = pmx - pnx[j], dy = pmy - pny[j], dz = pmz - pnz[j];
                float d = sqrtf(dx*dx + dy*dy + dz*dz);
                float val = s[i][j][r] * scale + sig * d;
                sv[j] = val;
                mx = fmaxf(mx, val);
            }
            #pragma unroll
            for (int off = 1; off < 16; off <<= 1) mx = fmaxf(mx, __shfl_xor(mx, off, 16));
            float sum = 0.f;
            #pragma unroll
            for (int j = 0; j < 8; ++j) {
                float p = __expf(sv[j] - mx);
                sum += p;
                Ps[(size_t)m*136 + j*16 + lane16] = f2b(p);
            }
            #pragma unroll
            for (int off = 1; off < 16; off <<= 1) sum += __shfl_xor(sum, off, 16);
            l[i][r] = sum;
        }
    __syncthreads();

    f32x4 o[2][2];
    #pragma unroll
    for (int i = 0; i < 2; ++i)
        #pragma unroll
        for (int nf = 0; nf < 2; ++nf) o[i][nf] = zero;
    #pragma unroll
    for (int c = 0; c < 4; ++c) {
        bf16x8 pa[2];
        #pragma unroll
        for (int i = 0; i < 2; ++i)
            pa[i] = *(const bf16x8*)&Ps[(wave*32 + i*16 + lane16)*136 + c*32 + quad*8];
        #pragma unroll
        for (int nf = 0; nf < 2; ++nf) {
            bf16x8 vb = *(const bf16x8*)&Vt[(nf*16 + lane16)*136 + c*32 + quad*8];
            #pragma unroll
            for (int i = 0; i < 2; ++i)
                o[i][nf] = __builtin_amdgcn_mfma_f32_16x16x32_bf16(pa[i], vb, o[i][nf], 0, 0, 0);
        }
    }

    #pragma unroll
    for (int i = 0; i < 2; ++i)
        #pragma unroll
        for (int nf = 0; nf < 2; ++nf)
            #pragma unroll
            for (int r = 0; r < 4; ++r) {
                int m = wave*32 + i*16 + quad*4 + r;
                out[(size_t)(ball*128 + m)*256 + h*32 + nf*16 + lane16] = f2b(o[i][nf][r] / l[i][r]);
            }
}

// ---------------------------------------------------------------------------
extern "C" void kernel_launch(void* const* d_in, const int* in_sizes, int n_in,
                              void* d_out, int out_size, void* d_ws, size_t ws_size,
                              hipStream_t stream)
{
    const float* x      = (const float*)d_in[0];
    const float* pos    = (const float*)d_in[1];
    const float* qkv_w  = (const float*)d_in[3];
    const float* qkv_b  = (const float*)d_in[4];
    const float* proj_w = (const float*)d_in[5];
    const float* proj_b = (const float*)d_in[6];
    const float* pe_w   = (const float*)d_in[7];
    const float* pe_b   = (const float*)d_in[8];
    const float* sigma  = (const float*)d_in[9];
    const float* n1w    = (const float*)d_in[10];
    const float* n2w    = (const float*)d_in[11];
    const float* w1w    = (const float*)d_in[12];
    const float* w1b    = (const float*)d_in[13];
    const float* w2w    = (const float*)d_in[14];
    const float* w2b    = (const float*)d_in[15];
    const float* w3w    = (const float*)d_in[16];
    const float* w3b    = (const float*)d_in[17];

    const int N = in_sizes[0] / 256;     // 131072 tokens
    float* out = (float*)d_out;

    unsigned short* wb      = (unsigned short*)d_ws;
    unsigned short* qkv_wb  = wb;
    unsigned short* proj_wb = wb + 196608;
    unsigned short* w1wb    = wb + 262144;
    unsigned short* w2wb    = wb + 524288;
    unsigned short* w3wb    = wb + 786432;

    int C = 1;
    while (2097152 + (size_t)(N / C) * 2560 > ws_size && C < 256) C <<= 1;
    const int R = N / C;
    unsigned short* regA = wb + 1048576;
    unsigned short* regB = regA + (size_t)R * 1024;

    // 0. weights f32 -> bf16
    k_cvt5<<<1024, 256, 0, stream>>>(qkv_w, proj_w, w1w, w2w, w3w, wb);

    for (int c = 0; c < C; ++c) {
        const size_t row0 = (size_t)c * R;
        const float* x_c   = x   + row0 * 256;
        const float* pos_c = pos + row0 * 3;
        float* out_c = out + row0 * 256;
        const int nball_c = R / 128;
        const int nx = R / 128;

        // 1. xpe = rmsnorm(x, n1w) + rel @ pe_w^T + pe_b    -> regB (bf16)
        k_norm1_pe<<<nball_c, 256, 0, stream>>>(x_c, pos_c, n1w, pe_w, pe_b, regB);
        // 2. qkv = xpe @ qkv_w^T + qkv_b                    -> regA (R x 768 bf16)
        k_gemm_bias<<<nx * 6, 256, 0, stream>>>(regB, qkv_wb, qkv_b, nullptr, regA, 256, 768, 1, 6);
        // 3. attention                                      -> regB (R x 256 bf16)
        k_attn<<<nball_c * 8, 256, 0, stream>>>(regA, pos_c, sigma, regB);
        // 4. x2 = x + attn @ proj_w^T + proj_b              -> d_out rows (f32)
        k_gemm_bias<<<nx * 2, 256, 0, stream>>>(regB, proj_wb, proj_b, x_c, out_c, 256, 256, 0, 2);
        // 5. h2 = rmsnorm(x2, n2w)                          -> regB (bf16)
        k_rmsnorm<<<R/4, 256, 0, stream>>>(out_c, n2w, regB);
        // 6. gv = silu(h2@w1^T + b1) * (h2@w2^T + b2)       -> regA (R x 1024 bf16)
        k_gemm_swiglu<<<nx * 16, 256, 0, stream>>>(regB, w1wb, w2wb, w1b, w2b, regA, 256, 16);
        // 7. out = x2 + gv @ w3^T + b3 (in-place residual)  -> d_out rows (f32)
        k_gemm_bias<<<nx * 2, 256, 0, stream>>>(regA, w3wb, w3b, out_c, out_c, 1024, 256, 0, 2);
    }
}

// Round 6
// 1065.539 us; speedup vs baseline: 1.1430x; 1.1430x over previous
//
#include <hip/hip_runtime.h>

typedef __bf16 bf16x8 __attribute__((ext_vector_type(8)));
typedef float f32x4 __attribute__((ext_vector_type(4)));

__device__ __forceinline__ float b2f(unsigned short u) {
    union { unsigned int i; float f; } v; v.i = ((unsigned int)u) << 16; return v.f;
}
__device__ __forceinline__ unsigned short f2b(float f) {
    union { float f; unsigned int i; } v; v.f = f;
    unsigned int r = (v.i + 0x7fffu + ((v.i >> 16) & 1u)) >> 16;
    return (unsigned short)r;
}

// async global -> LDS, 16B per lane. LDS dest is wave-uniform base + lane*16.
__device__ __forceinline__ void gload16(const void* g, void* l) {
    __builtin_amdgcn_global_load_lds(
        (const __attribute__((address_space(1))) unsigned int*)g,
        (__attribute__((address_space(3))) unsigned int*)l,
        16, 0, 0);
}

// XCD-chunked block mapping (T1): blocks sharing an A row-panel (same bx, all
// by) run back-to-back on the SAME XCD -> panel fetched into that XCD's L2
// once. Bijective when nx%8==0: bid=(xcd, s), s=(xl, by); bx=xcd*(nx/8)+xl.
__device__ __forceinline__ void xcd_map(int bid, int nx, int ny, int& bx, int& by) {
    if ((nx & 7) == 0) {
        int xcd = bid & 7;
        int s   = bid >> 3;
        int xl  = s / ny;
        by = s - xl * ny;
        bx = xcd * (nx >> 3) + xl;
    } else {
        bx = bid / ny;
        by = bid - bx * ny;
    }
}

// ---------------------------------------------------------------------------
// Convert the 5 weight matrices f32 -> bf16 into workspace (once per launch).
// ---------------------------------------------------------------------------
__global__ __launch_bounds__(256)
void k_cvt5(const float* __restrict__ s0, const float* __restrict__ s1,
            const float* __restrict__ s2, const float* __restrict__ s3,
            const float* __restrict__ s4, unsigned short* __restrict__ dst)
{
    size_t gid = ((size_t)blockIdx.x * 256 + threadIdx.x) * 4;
    const float* src; size_t off;
    if      (gid < 196608) { src = s0; off = 0; }
    else if (gid < 262144) { src = s1; off = 196608; }
    else if (gid < 524288) { src = s2; off = 262144; }
    else if (gid < 786432) { src = s3; off = 524288; }
    else                   { src = s4; off = 786432; }
    float4 v = *(const float4*)(src + (gid - off));
    uint2 pk;
    pk.x = (unsigned int)f2b(v.x) | ((unsigned int)f2b(v.y) << 16);
    pk.y = (unsigned int)f2b(v.z) | ((unsigned int)f2b(v.w) << 16);
    *(uint2*)(dst + gid) = pk;
}

// ---------------------------------------------------------------------------
// Kernel 1: h = rmsnorm(x, norm1_w); xpe = h + rel @ pe_w^T + pe_b  (bf16 out)
// ---------------------------------------------------------------------------
__global__ __launch_bounds__(256)
void k_norm1_pe(const float* __restrict__ x,
                const float* __restrict__ pos,
                const float* __restrict__ n1w,
                const float* __restrict__ pew,
                const float* __restrict__ peb,
                unsigned short* __restrict__ out)
{
    __shared__ float spw0[256], spw1[256], spw2[256], speb[256], snw[256];
    __shared__ float px[128], py[128], pz[128];
    __shared__ float mean[3];
    const int tid = threadIdx.x;
    const int ball = blockIdx.x;

    spw0[tid] = pew[tid*3+0]; spw1[tid] = pew[tid*3+1]; spw2[tid] = pew[tid*3+2];
    speb[tid] = peb[tid];     snw[tid]  = n1w[tid];
    if (tid < 128) {
        const float* pp = pos + (size_t)(ball*128 + tid)*3;
        px[tid] = pp[0]; py[tid] = pp[1]; pz[tid] = pp[2];
    }
    __syncthreads();
    if (tid < 3) {
        const float* arr = (tid==0) ? px : (tid==1) ? py : pz;
        float s = 0.f;
        for (int i = 0; i < 128; ++i) s += arr[i];
        mean[tid] = s * (1.0f/128.0f);
    }
    __syncthreads();

    const int wave = tid >> 6, lane = tid & 63;
    const float m0 = mean[0], m1 = mean[1], m2 = mean[2];
    for (int tok = wave; tok < 128; tok += 4) {
        size_t row = (size_t)(ball*128 + tok);
        float4 xv = *(const float4*)(x + row*256 + lane*4);
        float xf[4] = { xv.x, xv.y, xv.z, xv.w };
        float ss = xf[0]*xf[0] + xf[1]*xf[1] + xf[2]*xf[2] + xf[3]*xf[3];
        #pragma unroll
        for (int off = 1; off < 64; off <<= 1) ss += __shfl_xor(ss, off);
        float rstd = rsqrtf(ss * (1.0f/256.0f) + 1e-6f);
        float r0 = px[tok] - m0, r1 = py[tok] - m1, r2 = pz[tok] - m2;
        unsigned short o[4];
        #pragma unroll
        for (int k = 0; k < 4; ++k) {
            int j = lane*4 + k;
            float hv = xf[k] * rstd * snw[j];
            o[k] = f2b(hv + r0*spw0[j] + r1*spw1[j] + r2*spw2[j] + speb[j]);
        }
        uint2 pk;
        pk.x = (unsigned int)o[0] | ((unsigned int)o[1] << 16);
        pk.y = (unsigned int)o[2] | ((unsigned int)o[3] << 16);
        *(uint2*)(out + row*256 + lane*4) = pk;
    }
}

// ---------------------------------------------------------------------------
// rmsnorm only (norm2): f32 in, bf16 out, wave-per-token
// ---------------------------------------------------------------------------
__global__ __launch_bounds__(256)
void k_rmsnorm(const float* __restrict__ x,
               const float* __restrict__ w,
               unsigned short* __restrict__ out)
{
    const int lane = threadIdx.x & 63;
    const size_t token = (size_t)blockIdx.x*4 + (threadIdx.x >> 6);
    float4 xv = *(const float4*)(x + token*256 + lane*4);
    float xf[4] = { xv.x, xv.y, xv.z, xv.w };
    float ss = xf[0]*xf[0] + xf[1]*xf[1] + xf[2]*xf[2] + xf[3]*xf[3];
    #pragma unroll
    for (int off = 1; off < 64; off <<= 1) ss += __shfl_xor(ss, off);
    float rstd = rsqrtf(ss * (1.0f/256.0f) + 1e-6f);
    float4 wv = *(const float4*)(w + lane*4);
    unsigned short o[4] = { f2b(xf[0]*rstd*wv.x), f2b(xf[1]*rstd*wv.y),
                            f2b(xf[2]*rstd*wv.z), f2b(xf[3]*rstd*wv.w) };
    uint2 pk;
    pk.x = (unsigned int)o[0] | ((unsigned int)o[1] << 16);
    pk.y = (unsigned int)o[2] | ((unsigned int)o[3] << 16);
    *(uint2*)(out + token*256 + lane*4) = pk;
}

// ---------------------------------------------------------------------------
// GEMM mainloop: C(128x128) = A(M,K) @ B(N,K)^T, bf16, fp32 acc.
// 2-barrier single-buffer schedule (proven round 2).
// LDS slot permutation reconciles BOTH constraints (round-4 lesson:
// fragment-ordered staging killed global coalescing, -27%):
//  - STAGING stays quarter-wave coalesced (4 contiguous 64B rows per 16
//    lanes, as round 2): lane -> row (lane>>2), chunk (lane&3)^((lane>>3)&3).
//    So linear LDS slot s holds global (row s>>2, chunk (s&3)^((s>>3)&3)).
//  - READ: compute lane l (needs row l&15, chunk l>>4) reads slot
//    s(l) = ((l&15)<<2) | ((l>>4) ^ ((l>>1)&3)).  Within every 8-lane
//    phase s%8 is a full permutation -> all 32 banks per 128B -> conflict-
//    free (round 3/4 verified the measurement method: SQ_LDS_BANK_CONFLICT=0).
// ---------------------------------------------------------------------------
__device__ __forceinline__ void gemm_mainloop_bt(
    const unsigned short* __restrict__ A, const unsigned short* __restrict__ B,
    int K, int m0, int n0, int tid,
    unsigned short* sA, unsigned short* sB, f32x4 (&acc)[4][4])
{
    const int lane = tid & 63;
    const int wave = tid >> 6;
    // staging: wave stages subtiles {2w, 2w+1}; coalesced rows
    const int srow = wave * 32 + (lane >> 2);
    const int scol = (((lane & 3) ^ ((lane >> 3) & 3)) << 3);
    const unsigned short* pA = A + (size_t)(m0 + srow) * K + scol;
    const unsigned short* pB = B + (size_t)(n0 + srow) * K + scol;
    const size_t row16 = (size_t)16 * K;
    unsigned short* lA = sA + wave * 1024;
    unsigned short* lB = sB + wave * 1024;
    // read: permuted slot within each 1024B subtile
    const int slot = ((lane & 15) << 2) | ((lane >> 4) ^ ((lane >> 1) & 3));
    const int aBase = (wave >> 1) * 2048 + slot * 8;   // + i*512
    const int bBase = (wave & 1) * 2048 + slot * 8;    // + j*512

    for (int k0 = 0; k0 < K; k0 += 32) {
        __syncthreads();
        gload16(pA + k0,         lA);
        gload16(pA + row16 + k0, lA + 512);
        gload16(pB + k0,         lB);
        gload16(pB + row16 + k0, lB + 512);
        __syncthreads();   // vmcnt(0) drain = tile handoff
        bf16x8 af[4], bfr[4];
        #pragma unroll
        for (int i = 0; i < 4; ++i) af[i]  = *(const bf16x8*)&sA[aBase + i*512];
        #pragma unroll
        for (int j = 0; j < 4; ++j) bfr[j] = *(const bf16x8*)&sB[bBase + j*512];
        #pragma unroll
        for (int i = 0; i < 4; ++i)
            #pragma unroll
            for (int j = 0; j < 4; ++j)
                acc[i][j] = __builtin_amdgcn_mfma_f32_16x16x32_bf16(af[i], bfr[j], acc[i][j], 0, 0, 0);
    }
}

// Generic GEMM + f32 bias (+ optional f32 residual); output bf16 or f32.
__global__ __launch_bounds__(256, 2)
void k_gemm_bias(const unsigned short* __restrict__ A,
                 const unsigned short* __restrict__ B,
                 const float* __restrict__ bias,
                 const float* residual,
                 void* C, int K, int Ncols, int outBf16, int ny)
{
    __shared__ __align__(16) unsigned short sA[128*32];
    __shared__ __align__(16) unsigned short sB[128*32];
    const int tid = threadIdx.x;
    int bx, by;
    xcd_map(blockIdx.x, gridDim.x / ny, ny, bx, by);
    const int m0 = bx * 128, n0 = by * 128;
    f32x4 zero = {0.f, 0.f, 0.f, 0.f};
    f32x4 acc[4][4];
    #pragma unroll
    for (int i = 0; i < 4; ++i)
        #pragma unroll
        for (int j = 0; j < 4; ++j) acc[i][j] = zero;

    gemm_mainloop_bt(A, B, K, m0, n0, tid, sA, sB, acc);

    const int lane = tid & 63, lane16 = lane & 15, quad = lane >> 4;
    const int wave = tid >> 6, wm = (wave >> 1) * 64, wn = (wave & 1) * 64;
    #pragma unroll
    for (int i = 0; i < 4; ++i)
        #pragma unroll
        for (int j = 0; j < 4; ++j) {
            int n = n0 + wn + j*16 + lane16;
            float bj = bias[n];
            #pragma unroll
            for (int r = 0; r < 4; ++r) {
                int m = m0 + wm + i*16 + quad*4 + r;
                size_t idx = (size_t)m * Ncols + n;
                float v = acc[i][j][r] + bj;
                if (residual) v += residual[idx];
                if (outBf16) ((unsigned short*)C)[idx] = f2b(v);
                else         ((float*)C)[idx] = v;
            }
        }
}

// ---------------------------------------------------------------------------
// SwiGLU dual GEMM: gv = silu(A@B1^T + b1) * (A@B2^T + b2) -> bf16, Ncols=1024
// Block tile 128x64, wave tile 64x32; coalesced staging + permuted-slot read.
// Wave stages A subtiles {2w,2w+1}, B1 subtile {w}, B2 subtile {w}.
// ---------------------------------------------------------------------------
__global__ __launch_bounds__(256, 3)
void k_gemm_swiglu(const unsigned short* __restrict__ A,
                   const unsigned short* __restrict__ B1,
                   const unsigned short* __restrict__ B2,
                   const float* __restrict__ b1,
                   const float* __restrict__ b2,
                   unsigned short* __restrict__ C, int K, int ny)
{
    __shared__ __align__(16) unsigned short sA[128*32];
    __shared__ __align__(16) unsigned short sB1[64*32];
    __shared__ __align__(16) unsigned short sB2[64*32];
    const int tid = threadIdx.x;
    int bx, by;
    xcd_map(blockIdx.x, gridDim.x / ny, ny, bx, by);
    const int m0 = bx * 128, n0 = by * 64;
    const int lane = tid & 63, lane16 = lane & 15, quad = lane >> 4;
    const int wave = tid >> 6;
    const int wm = (wave >> 1) * 64, wn = (wave & 1) * 32;
    const int srowA = wave * 32 + (lane >> 2);
    const int srowB = wave * 16 + (lane >> 2);
    const int scol  = (((lane & 3) ^ ((lane >> 3) & 3)) << 3);
    const unsigned short* pA  = A  + (size_t)(m0 + srowA) * K + scol;
    const unsigned short* pB1 = B1 + (size_t)(n0 + srowB) * K + scol;
    const unsigned short* pB2 = B2 + (size_t)(n0 + srowB) * K + scol;
    const size_t row16 = (size_t)16 * K;
    unsigned short* lA  = sA  + wave * 1024;
    unsigned short* lB1 = sB1 + wave * 512;
    unsigned short* lB2 = sB2 + wave * 512;
    const int slot = ((lane & 15) << 2) | ((lane >> 4) ^ ((lane >> 1) & 3));
    const int aBase = (wave >> 1) * 2048 + slot * 8;   // + i*512, i<4
    const int bBase = (wave & 1) * 1024 + slot * 8;    // + j*512, j<2

    f32x4 zero = {0.f, 0.f, 0.f, 0.f};
    f32x4 accg[4][2], accv[4][2];
    #pragma unroll
    for (int i = 0; i < 4; ++i)
        #pragma unroll
        for (int j = 0; j < 2; ++j) { accg[i][j] = zero; accv[i][j] = zero; }

    for (int k0 = 0; k0 < K; k0 += 32) {
        __syncthreads();
        gload16(pA + k0,         lA);
        gload16(pA + row16 + k0, lA + 512);
        gload16(pB1 + k0,        lB1);
        gload16(pB2 + k0,        lB2);
        __syncthreads();
        bf16x8 af[4], bg[2], bv[2];
        #pragma unroll
        for (int i = 0; i < 4; ++i) af[i] = *(const bf16x8*)&sA[aBase + i*512];
        #pragma unroll
        for (int j = 0; j < 2; ++j) {
            bg[j] = *(const bf16x8*)&sB1[bBase + j*512];
            bv[j] = *(const bf16x8*)&sB2[bBase + j*512];
        }
        #pragma unroll
        for (int i = 0; i < 4; ++i)
            #pragma unroll
            for (int j = 0; j < 2; ++j) {
                accg[i][j] = __builtin_amdgcn_mfma_f32_16x16x32_bf16(af[i], bg[j], accg[i][j], 0, 0, 0);
                accv[i][j] = __builtin_amdgcn_mfma_f32_16x16x32_bf16(af[i], bv[j], accv[i][j], 0, 0, 0);
            }
    }

    #pragma unroll
    for (int i = 0; i < 4; ++i)
        #pragma unroll
        for (int j = 0; j < 2; ++j) {
            int n = n0 + wn + j*16 + lane16;
            float bjg = b1[n], bjv = b2[n];
            #pragma unroll
            for (int r = 0; r < 4; ++r) {
                int m = m0 + wm + i*16 + quad*4 + r;
                float g  = accg[i][j][r] + bjg;
                float vv = accv[i][j][r] + bjv;
                float sg = 1.0f / (1.0f + __expf(-g));
                C[(size_t)m * 1024 + n] = f2b(g * sg * vv);
            }
        }
}

// ---------------------------------------------------------------------------
// Attention: one block per (ball, head). 256 threads = 4 waves.
// ---------------------------------------------------------------------------
__global__ __launch_bounds__(256, 2)
void k_attn(const unsigned short* __restrict__ qkv,
            const float* __restrict__ pos,
            const float* __restrict__ sigma,
            unsigned short* __restrict__ out)
{
    __shared__ __align__(16) unsigned short Qs[128*40];
    __shared__ __align__(16) unsigned short Ks[128*40];
    __shared__ __align__(16) unsigned short Vt[32*136];
    __shared__ __align__(16) unsigned short Ps[128*136];
    __shared__ float px[128], py[128], pz[128];

    int ball, h;
    xcd_map(blockIdx.x, gridDim.x >> 3, 8, ball, h);
    const int tid  = threadIdx.x;

    {
        int tok = tid >> 1;
        int e0  = (tid & 1) * 16;
        const unsigned short* rowp = qkv + (size_t)(ball*128 + tok)*768 + h*96 + e0*3;
        unsigned short u[48];
        #pragma unroll
        for (int c = 0; c < 6; ++c) *(uint4*)&u[c*8] = *(const uint4*)(rowp + c*8);
        #pragma unroll
        for (int e = 0; e < 16; ++e) {
            Qs[tok*40 + e0 + e]    = u[e*3 + 0];
            Ks[tok*40 + e0 + e]    = u[e*3 + 1];
            Vt[(e0 + e)*136 + tok] = u[e*3 + 2];
        }
    }
    if (tid < 128) {
        const float* pp = pos + (size_t)(ball*128 + tid)*3;
        px[tid] = pp[0]; py[tid] = pp[1]; pz[tid] = pp[2];
    }
    __syncthreads();

    const int wave = tid >> 6, lane = tid & 63, lane16 = lane & 15, quad = lane >> 4;
    const float sig = sigma[h];
    const float scale = 0.17677669529663687f;  // 1/sqrt(32)
    f32x4 zero = {0.f, 0.f, 0.f, 0.f};

    f32x4 s[2][8];
    {
        bf16x8 a[2];
        #pragma unroll
        for (int i = 0; i < 2; ++i)
            a[i] = *(const bf16x8*)&Qs[(wave*32 + i*16 + lane16)*40 + quad*8];
        #pragma unroll
        for (int j = 0; j < 8; ++j) {
            bf16x8 b = *(const bf16x8*)&Ks[(j*16 + lane16)*40 + quad*8];
            #pragma unroll
            for (int i = 0; i < 2; ++i)
                s[i][j] = __builtin_amdgcn_mfma_f32_16x16x32_bf16(a[i], b, zero, 0, 0, 0);
        }
    }

    float pnx[8], pny[8], pnz[8];
    #pragma unroll
    for (int j = 0; j < 8; ++j) {
        int n = j*16 + lane16;
        pnx[j] = px[n]; pny[j] = py[n]; pnz[j] = pz[n];
    }
    float l[2][4];
    #pragma unroll
    for (int i = 0; i < 2; ++i)
        #pragma unroll
        for (int r = 0; r < 4; ++r) {
            int m = wave*32 + i*16 + quad*4 + r;
            float pmx = px[m], pmy = py[m], pmz = pz[m];
            float sv[8];
            float mx = -1e30f;
            #pragma unroll
            for (int j = 0; j < 8; ++j) {
                float dx = pmx - pnx[j], dy = pmy - pny[j], dz = pmz - pnz[j];
                float d = sqrtf(dx*dx + dy*dy + dz*dz);
                float val = s[i][j][r] * scale + sig * d;
                sv[j] = val;
                mx = fmaxf(mx, val);
            }
            #pragma unroll
            for (int off = 1; off < 16; off <<= 1) mx = fmaxf(mx, __shfl_xor(mx, off, 16));
            float sum = 0.f;
            #pragma unroll
            for (int j = 0; j < 8; ++j) {
                float p = __expf(sv[j] - mx);
                sum += p;
                Ps[(size_t)m*136 + j*16 + lane16] = f2b(p);
            }
            #pragma unroll
            for (int off = 1; off < 16; off <<= 1) sum += __shfl_xor(sum, off, 16);
            l[i][r] = sum;
        }
    __syncthreads();

    f32x4 o[2][2];
    #pragma unroll
    for (int i = 0; i < 2; ++i)
        #pragma unroll
        for (int nf = 0; nf < 2; ++nf) o[i][nf] = zero;
    #pragma unroll
    for (int c = 0; c < 4; ++c) {
        bf16x8 pa[2];
        #pragma unroll
        for (int i = 0; i < 2; ++i)
            pa[i] = *(const bf16x8*)&Ps[(wave*32 + i*16 + lane16)*136 + c*32 + quad*8];
        #pragma unroll
        for (int nf = 0; nf < 2; ++nf) {
            bf16x8 vb = *(const bf16x8*)&Vt[(nf*16 + lane16)*136 + c*32 + quad*8];
            #pragma unroll
            for (int i = 0; i < 2; ++i)
                o[i][nf] = __builtin_amdgcn_mfma_f32_16x16x32_bf16(pa[i], vb, o[i][nf], 0, 0, 0);
        }
    }

    #pragma unroll
    for (int i = 0; i < 2; ++i)
        #pragma unroll
        for (int nf = 0; nf < 2; ++nf)
            #pragma unroll
            for (int r = 0; r < 4; ++r) {
                int m = wave*32 + i*16 + quad*4 + r;
                out[(size_t)(ball*128 + m)*256 + h*32 + nf*16 + lane16] = f2b(o[i][nf][r] / l[i][r]);
            }
}

// ---------------------------------------------------------------------------
extern "C" void kernel_launch(void* const* d_in, const int* in_sizes, int n_in,
                              void* d_out, int out_size, void* d_ws, size_t ws_size,
                              hipStream_t stream)
{
    const float* x      = (const float*)d_in[0];
    const float* pos    = (const float*)d_in[1];
    const float* qkv_w  = (const float*)d_in[3];
    const float* qkv_b  = (const float*)d_in[4];
    const float* proj_w = (const float*)d_in[5];
    const float* proj_b = (const float*)d_in[6];
    const float* pe_w   = (const float*)d_in[7];
    const float* pe_b   = (const float*)d_in[8];
    const float* sigma  = (const float*)d_in[9];
    const float* n1w    = (const float*)d_in[10];
    const float* n2w    = (const float*)d_in[11];
    const float* w1w    = (const float*)d_in[12];
    const float* w1b    = (const float*)d_in[13];
    const float* w2w    = (const float*)d_in[14];
    const float* w2b    = (const float*)d_in[15];
    const float* w3w    = (const float*)d_in[16];
    const float* w3b    = (const float*)d_in[17];

    const int N = in_sizes[0] / 256;     // 131072 tokens
    float* out = (float*)d_out;

    unsigned short* wb      = (unsigned short*)d_ws;
    unsigned short* qkv_wb  = wb;
    unsigned short* proj_wb = wb + 196608;
    unsigned short* w1wb    = wb + 262144;
    unsigned short* w2wb    = wb + 524288;
    unsigned short* w3wb    = wb + 786432;

    int C = 1;
    while (2097152 + (size_t)(N / C) * 2560 > ws_size && C < 256) C <<= 1;
    const int R = N / C;
    unsigned short* regA = wb + 1048576;
    unsigned short* regB = regA + (size_t)R * 1024;

    // 0. weights f32 -> bf16
    k_cvt5<<<1024, 256, 0, stream>>>(qkv_w, proj_w, w1w, w2w, w3w, wb);

    for (int c = 0; c < C; ++c) {
        const size_t row0 = (size_t)c * R;
        const float* x_c   = x   + row0 * 256;
        const float* pos_c = pos + row0 * 3;
        float* out_c = out + row0 * 256;
        const int nball_c = R / 128;
        const int nx = R / 128;

        // 1. xpe = rmsnorm(x, n1w) + rel @ pe_w^T + pe_b    -> regB (bf16)
        k_norm1_pe<<<nball_c, 256, 0, stream>>>(x_c, pos_c, n1w, pe_w, pe_b, regB);
        // 2. qkv = xpe @ qkv_w^T + qkv_b                    -> regA (R x 768 bf16)
        k_gemm_bias<<<nx * 6, 256, 0, stream>>>(regB, qkv_wb, qkv_b, nullptr, regA, 256, 768, 1, 6);
        // 3. attention                                      -> regB (R x 256 bf16)
        k_attn<<<nball_c * 8, 256, 0, stream>>>(regA, pos_c, sigma, regB);
        // 4. x2 = x + attn @ proj_w^T + proj_b              -> d_out rows (f32)
        k_gemm_bias<<<nx * 2, 256, 0, stream>>>(regB, proj_wb, proj_b, x_c, out_c, 256, 256, 0, 2);
        // 5. h2 = rmsnorm(x2, n2w)                          -> regB (bf16)
        k_rmsnorm<<<R/4, 256, 0, stream>>>(out_c, n2w, regB);
        // 6. gv = silu(h2@w1^T + b1) * (h2@w2^T + b2)       -> regA (R x 1024 bf16)
        k_gemm_swiglu<<<nx * 16, 256, 0, stream>>>(regB, w1wb, w2wb, w1b, w2b, regA, 256, 16);
        // 7. out = x2 + gv @ w3^T + b3 (in-place residual)  -> d_out rows (f32)
        k_gemm_bias<<<nx * 2, 256, 0, stream>>>(regA, w3wb, w3b, out_c, out_c, 1024, 256, 0, 2);
    }
}